// Round 3
// baseline (625.876 us; speedup 1.0000x reference)
//
#include <hip/hip_runtime.h>

// Conv2DProduct: one-hot "sparse product" conv in log space.
// out[b,i,j,o] = x[b,2i,2j, o&31] + x[b,2i,2j+1, (o>>5)&15]
//             + x[b,2i+1,2j, 0]   + x[b,2i+1,2j+1, 0]
// Shapes: x [64,128,128,32] f32, out [64,64,64,512] f32.
// The one-hot kernel input (d_in[1]) is mathematically redundant — ignored.
//
// R3 == R2 with the compile fix: nontemporal stores need a clang native
// vector type (ext_vector_type), not HIP's float4 class. Same probe:
// stream the 512 MiB output past L2/L3 write-allocate.

typedef float f32x4 __attribute__((ext_vector_type(4)));

constexpr int B     = 64;
constexpr int H     = 128;
constexpr int W     = 128;
constexpr int C_IN  = 32;
constexpr int HO    = 64;
constexpr int WO    = 64;
constexpr int C_OUT = 512;

constexpr int NPIX    = B * HO * WO;          // 262,144 output pixels
constexpr int TOTAL_U = NPIX * 64;            // work-items (each -> 2 float4)
constexpr int BLOCK   = 256;
constexpr int GRID    = 8192;
constexpr int STRIDE  = BLOCK * GRID;         // 2,097,152 threads
constexpr int ITERS   = TOTAL_U / STRIDE;     // 8 (exact)

static_assert(TOTAL_U % STRIDE == 0, "exact grid-stride");

__global__ __launch_bounds__(BLOCK) void conv2d_product_kernel(
    const float* __restrict__ x, float* __restrict__ out) {
    const int t = blockIdx.x * BLOCK + threadIdx.x;

#pragma unroll
    for (int k = 0; k < ITERS; ++k) {
        const int u   = t + k * STRIDE;
        const int o4h = u & 63;       // lane id; half-index into 128 float4s/pixel
        const int pix = u >> 6;       // b*HO*WO + i*WO + j  (wave-uniform)

        // x offset of input pixel (2i, 2j) in floats:
        //   b*524288 + i*8192 + j*64 == (pix + (pix & ~63)) << 6
        const int xoff = (pix + (pix & ~63)) << 6;
        const float* xb = x + xoff;

        // cell (0,0): 4 consecutive channels, shared by both output halves
        const f32x4 a = *(const f32x4*)(xb + ((o4h & 7) << 2));

        // cell (0,1): channel (o>>5) for each half
        const int bi = C_IN + (o4h >> 3);
        const float b0 = xb[bi];          // half 0: channels (o>>5) in 0..7
        const float b1 = xb[bi + 8];      // half 1: channels 8..15

        // cells (1,0),(1,1): channel 0 of next row (wave-uniform broadcast)
        const float s = xb[W * C_IN] + xb[W * C_IN + C_IN];

        const float add0 = b0 + s;
        const float add1 = b1 + s;

        const f32x4 r0 = a + add0;
        const f32x4 r1 = a + add1;

        f32x4* op = (f32x4*)out + (((size_t)pix) << 7) + o4h;
        __builtin_nontemporal_store(r0, op);        // float4 index pix*128 + o4h
        __builtin_nontemporal_store(r1, op + 64);   // float4 index pix*128 + o4h + 64
    }
}

extern "C" void kernel_launch(void* const* d_in, const int* in_sizes, int n_in,
                              void* d_out, int out_size, void* d_ws, size_t ws_size,
                              hipStream_t stream) {
    const float* x = (const float*)d_in[0];
    float* out = (float*)d_out;
    conv2d_product_kernel<<<GRID, BLOCK, 0, stream>>>(x, out);
}

// Round 4
// 612.149 us; speedup vs baseline: 1.0224x; 1.0224x over previous
//
#include <hip/hip_runtime.h>

// Conv2DProduct: one-hot "sparse product" conv in log space.
// out[b,i,j,o] = x[b,2i,2j, o&31] + x[b,2i,2j+1, (o>>5)&15]
//             + x[b,2i+1,2j, 0]   + x[b,2i+1,2j+1, 0]
// Shapes: x [64,128,128,32] f32, out [64,64,64,512] f32.
// The one-hot kernel input (d_in[1]) is mathematically redundant — ignored.
//
// R4: fill-mimicking write schedule. 8192 waves (2048 blocks), each wave owns
// 32 CONSECUTIVE pixels = 64 KiB of contiguous output, written sequentially
// (few long write streams, like the 6.3 TB/s fillBuffer kernel), instead of
// many 2 KiB chunks strided by 64 MiB. Reads become a forward sweep too.
// Probes the last untested axis: DRAM page/channel locality of write streams.

typedef float f32x4 __attribute__((ext_vector_type(4)));

constexpr int B     = 64;
constexpr int H     = 128;
constexpr int W     = 128;
constexpr int C_IN  = 32;
constexpr int HO    = 64;
constexpr int WO    = 64;
constexpr int C_OUT = 512;

constexpr int NPIX  = B * HO * WO;        // 262,144 output pixels
constexpr int PPW   = 32;                 // pixels per wave (contiguous run)
constexpr int WAVES = NPIX / PPW;         // 8192
constexpr int BLOCK = 256;
constexpr int GRID  = WAVES * 64 / BLOCK; // 2048 blocks (8 per CU)

static_assert(NPIX % PPW == 0, "exact partition");
// PPW=32 divides 64, and runs start at multiples of 32 -> a wave's pixel run
// never crosses a 64-pixel (output-row) boundary, so (p & ~63) is constant
// across the run and the input base advances uniformly by 64 floats/pixel.
static_assert(64 % PPW == 0, "run stays within one output row");

__global__ __launch_bounds__(BLOCK) void conv2d_product_kernel(
    const float* __restrict__ x, float* __restrict__ out) {
    const int t    = blockIdx.x * BLOCK + threadIdx.x;
    const int wave = t >> 6;      // global wave id, owns pixels [wave*PPW, +PPW)
    const int lane = t & 63;

    const int p0 = wave * PPW;
    // Input base of pixel p0's (2i, 2j) corner: (p + (p & ~63)) * 64 floats.
    const float* xr = x + (((size_t)(p0 + (p0 & ~63))) << 6);
    // Output float4 pointer for this lane at pixel p0.
    f32x4* op = (f32x4*)out + (((size_t)p0) << 7) + lane;

    const int ai = (lane & 7) << 2;      // cell(0,0) channel group
    const int bi = C_IN + (lane >> 3);   // cell(0,1) channel, half 0

#pragma unroll 4
    for (int m = 0; m < PPW; ++m) {
        const float* xb = xr + m * 64;

        // cell (0,0): 4 consecutive channels, shared by both output halves
        const f32x4 a = *(const f32x4*)(xb + ai);
        // cell (0,1): channel (o>>5) for each half
        const float b0 = xb[bi];
        const float b1 = xb[bi + 8];
        // cells (1,0),(1,1): channel 0 of next input row (wave-uniform)
        const float s = xb[W * C_IN] + xb[W * C_IN + C_IN];

        const f32x4 r0 = a + (b0 + s);
        const f32x4 r1 = a + (b1 + s);

        op[0]  = r0;   // float4 index p*128 + lane
        op[64] = r1;   // float4 index p*128 + lane + 64
        op += 128;     // next pixel: +2 KiB, contiguous wave stream
    }
}

extern "C" void kernel_launch(void* const* d_in, const int* in_sizes, int n_in,
                              void* d_out, int out_size, void* d_ws, size_t ws_size,
                              hipStream_t stream) {
    const float* x = (const float*)d_in[0];
    float* out = (float*)d_out;
    conv2d_product_kernel<<<GRID, BLOCK, 0, stream>>>(x, out);
}